// Round 1
// 85.150 us; speedup vs baseline: 1.0080x; 1.0080x over previous
//
#include <hip/hip_runtime.h>
#include <hip/hip_bf16.h>

typedef __attribute__((ext_vector_type(8))) __bf16 bf16x8;
typedef __attribute__((ext_vector_type(4))) float  f32x4;

constexpr int NN   = 2048;  // points per batch
constexpr int DD   = 128;   // dim
constexpr int TI   = 128;   // i-tile rows per block
constexpr int TJ   = 64;    // j-tile rows per block
constexpr int ROWB = 256;   // bytes per bf16 row (128 * 2)

// ---- async global->LDS, 16B per lane. LDS dest must be wave-uniform + lane*16,
// which our (t + iter*256)*16 indexing satisfies. Global src is per-lane.
__device__ __forceinline__ void gload_lds16(const void* g, void* l) {
    __builtin_amdgcn_global_load_lds(
        (const __attribute__((address_space(1))) void*)g,
        (__attribute__((address_space(3))) void*)l, 16, 0, 0);
}

// ============================================================================
// Prep: fp32 x -> bf16, stored XOR-swizzled (byte ^= (row&7)<<4 within the
// 256B row) so the main kernel can global_load_lds linearly and ds_read_b128
// conflict-free. Also per-row squared norms from the bf16-ROUNDED values so
// the diagonal sq_i + sq_i - 2*cross_ii cancels like the reference.
// ============================================================================
__global__ __launch_bounds__(256)
void edm_prep(const float* __restrict__ x, __bf16* __restrict__ xb,
              float* __restrict__ sq) {
    const int t  = threadIdx.x;
    const int rl = t >> 4;                 // row within this block's 16 rows
    const int c  = t & 15;                 // 16B chunk within row
    const int g  = blockIdx.x * 16 + rl;   // global row 0..8191 (= b*2048 + n)

    const float4* p = (const float4*)(x + (size_t)g * DD + c * 8);
    const float4 v0 = p[0];
    const float4 v1 = p[1];
    bf16x8 w;
    w[0] = (__bf16)v0.x; w[1] = (__bf16)v0.y;
    w[2] = (__bf16)v0.z; w[3] = (__bf16)v0.w;
    w[4] = (__bf16)v1.x; w[5] = (__bf16)v1.y;
    w[6] = (__bf16)v1.z; w[7] = (__bf16)v1.w;

    float s = 0.f;
    #pragma unroll
    for (int j = 0; j < 8; ++j) { const float f = (float)w[j]; s += f * f; }

    const int byte = (c * 16) ^ ((g & 7) << 4);   // bijective within the row
    *(bf16x8*)((char*)xb + (size_t)g * ROWB + byte) = w;

    // reduce the 16 chunk-sums of this row (lanes grouped by 16 within wave)
    s += __shfl_xor(s, 1);
    s += __shfl_xor(s, 2);
    s += __shfl_xor(s, 4);
    s += __shfl_xor(s, 8);
    if (c == 0) sq[g] = s;
}

// ============================================================================
// Main: stage bf16 tiles via global_load_lds (linear LDS, pre-swizzled src),
// MFMA with SWAPPED operands so the reg-dim of the C-fragment runs along j
// (memory-contiguous) -> f32x4 epilogue stores.
// ============================================================================
__global__ __launch_bounds__(256, 3)
void edm_main(const __bf16* __restrict__ xb, const float* __restrict__ sq,
              float* __restrict__ out) {
    __shared__ __align__(16) char As[TI * ROWB];   // 32 KB
    __shared__ __align__(16) char Bs[TJ * ROWB];   // 16 KB

    const int t  = threadIdx.x;
    const int jt = blockIdx.x;   // 0..31
    const int it = blockIdx.y;   // 0..15
    const int b  = blockIdx.z;   // 0..3

    const char* xbase = (const char*)xb + (size_t)b * NN * ROWB;
    const char* srcA  = xbase + (size_t)it * TI * ROWB;
    const char* srcB  = xbase + (size_t)jt * TJ * ROWB;

    // ---- async stage: A 32KB = 8 iters, B 16KB = 4 iters (16B/lane/iter)
    #pragma unroll
    for (int i = 0; i < 8; ++i) {
        const int off = (t + i * 256) * 16;
        gload_lds16(srcA + off, As + off);
    }
    #pragma unroll
    for (int i = 0; i < 4; ++i) {
        const int off = (t + i * 256) * 16;
        gload_lds16(srcB + off, Bs + off);
    }

    const int wave = t >> 6;
    const int lane = t & 63;
    const int wm = (wave >> 1) * 64;   // 0 or 64
    const int wn = (wave & 1) * 32;    // 0 or 32
    const int lm = lane & 15;
    const int q  = lane >> 4;          // quad 0..3
    const int swz = (lm & 7) << 4;     // row&7 == lm&7 for all frag rows

    // ---- prefetch norms from global (issues under the staging latency)
    const float* sqi = sq + b * NN + it * TI;
    const float* sqj = sq + b * NN + jt * TJ;
    float si[4];
    #pragma unroll
    for (int mf = 0; mf < 4; ++mf) si[mf] = sqi[wm + mf * 16 + lm];
    f32x4 sj[2];
    #pragma unroll
    for (int nf = 0; nf < 2; ++nf)
        sj[nf] = *(const f32x4*)(sqj + wn + nf * 16 + q * 4);

    __syncthreads();   // compiler drains vmcnt(0) here -> LDS tiles ready

    // ---- MFMA: wave computes 64x32 sub-tile; operands SWAPPED so
    // lane-dim = i (A rows), reg-dim = j (B rows, contiguous in memory).
    f32x4 acc[4][2] = {};
    #pragma unroll
    for (int ks = 0; ks < 4; ++ks) {
        const int cb = ks * 64 + q * 16;   // byte offset of this lane's k-chunk
        bf16x8 a[4], bb[2];
        #pragma unroll
        for (int mf = 0; mf < 4; ++mf) {
            const int row = wm + mf * 16 + lm;
            a[mf] = *(const bf16x8*)(As + row * ROWB + (cb ^ swz));
        }
        #pragma unroll
        for (int nf = 0; nf < 2; ++nf) {
            const int row = wn + nf * 16 + lm;
            bb[nf] = *(const bf16x8*)(Bs + row * ROWB + (cb ^ swz));
        }
        #pragma unroll
        for (int mf = 0; mf < 4; ++mf)
            #pragma unroll
            for (int nf = 0; nf < 2; ++nf)
                acc[mf][nf] = __builtin_amdgcn_mfma_f32_16x16x32_bf16(
                    bb[nf], a[mf], acc[mf][nf], 0, 0, 0);
    }

    // ---- epilogue: d = sqrt(max(si + sj - 2*cross, 0) + eps), f32x4 stores
    float* outp = out + ((size_t)b * NN + (size_t)it * TI) * NN + (size_t)jt * TJ;
    #pragma unroll
    for (int mf = 0; mf < 4; ++mf) {
        const int i = wm + mf * 16 + lm;           // output row (lane-dim)
        float* rowp = outp + (size_t)i * NN;
        const float base = si[mf];
        #pragma unroll
        for (int nf = 0; nf < 2; ++nf) {
            f32x4 d;
            #pragma unroll
            for (int r = 0; r < 4; ++r) {
                float d2 = base + sj[nf][r] - 2.0f * acc[mf][nf][r];
                d2 = fmaxf(d2, 0.0f);
                d[r] = sqrtf(d2 + 1e-7f);
            }
            *(f32x4*)(rowp + wn + nf * 16 + q * 4) = d;  // 16B contiguous in j
        }
    }
}

extern "C" void kernel_launch(void* const* d_in, const int* in_sizes, int n_in,
                              void* d_out, int out_size, void* d_ws, size_t ws_size,
                              hipStream_t stream) {
    const float* x = (const float*)d_in[0];
    float* out = (float*)d_out;
    // workspace: [0, 32KB) per-row norms (8192 f32), [32KB, 32KB+2MB) bf16 x
    float*  sqw = (float*)d_ws;
    __bf16* xbw = (__bf16*)((char*)d_ws + 32768);
    edm_prep<<<dim3((4 * NN) / 16), dim3(256), 0, stream>>>(x, xbw, sqw);
    edm_main<<<dim3(NN / TJ, NN / TI, 4), dim3(256), 0, stream>>>(xbw, sqw, out);
}

// Round 2
// 80.290 us; speedup vs baseline: 1.0690x; 1.0605x over previous
//
#include <hip/hip_runtime.h>
#include <hip/hip_bf16.h>
#include <math.h>

typedef __attribute__((ext_vector_type(8))) __bf16 bf16x8;
typedef __attribute__((ext_vector_type(4))) float  f32x4;

constexpr int NN   = 2048;  // points per batch
constexpr int DD   = 128;   // dim
constexpr int TI   = 128;   // i-tile rows per block
constexpr int TJ   = 64;    // j-tile rows
constexpr int NJI  = 4;     // j-tiles per block (persistent over 256 cols)
constexpr int ROWB = 256;   // bytes per bf16 row (128 * 2)

__device__ __forceinline__ void gload_lds16(const void* g, void* l) {
    __builtin_amdgcn_global_load_lds(
        (const __attribute__((address_space(1))) void*)g,
        (__attribute__((address_space(3))) void*)l, 16, 0, 0);
}

__device__ __forceinline__ float fast_sqrt(float v) {
#if __has_builtin(__builtin_amdgcn_sqrtf)
    return __builtin_amdgcn_sqrtf(v);   // v_sqrt_f32, ~1 ulp; absmax tol is 0.125
#else
    return sqrtf(v);
#endif
}

// ============================================================================
// Prep: fp32 x -> bf16, XOR-swizzled rows (byte ^= (row&7)<<4) so main can
// global_load_lds linearly and ds_read_b128 conflict-free. Norms from the
// bf16-ROUNDED values so the diagonal cancels like the reference.
// ============================================================================
__global__ __launch_bounds__(256)
void edm_prep(const float* __restrict__ x, __bf16* __restrict__ xb,
              float* __restrict__ sq) {
    const int t  = threadIdx.x;
    const int rl = t >> 4;
    const int c  = t & 15;
    const int g  = blockIdx.x * 16 + rl;   // global row (= b*2048 + n)

    const float4* p = (const float4*)(x + (size_t)g * DD + c * 8);
    const float4 v0 = p[0];
    const float4 v1 = p[1];
    bf16x8 w;
    w[0] = (__bf16)v0.x; w[1] = (__bf16)v0.y;
    w[2] = (__bf16)v0.z; w[3] = (__bf16)v0.w;
    w[4] = (__bf16)v1.x; w[5] = (__bf16)v1.y;
    w[6] = (__bf16)v1.z; w[7] = (__bf16)v1.w;

    float s = 0.f;
    #pragma unroll
    for (int j = 0; j < 8; ++j) { const float f = (float)w[j]; s += f * f; }

    const int byte = (c * 16) ^ ((g & 7) << 4);
    *(bf16x8*)((char*)xb + (size_t)g * ROWB + byte) = w;

    s += __shfl_xor(s, 1);
    s += __shfl_xor(s, 2);
    s += __shfl_xor(s, 4);
    s += __shfl_xor(s, 8);
    if (c == 0) sq[g] = s;
}

// ============================================================================
// Main: 512 blocks = exactly 2/CU (all resident, no tail). Each block:
// stage A once -> hold 16 A-frags in registers -> loop 4 j-tiles with
// double-buffered B staging (prefetch next B under current compute+stores).
// ============================================================================
__global__ __launch_bounds__(256, 2)
void edm_main(const __bf16* __restrict__ xb, const float* __restrict__ sq,
              float* __restrict__ out) {
    __shared__ __align__(16) char As[TI * ROWB];        // 32 KB
    __shared__ __align__(16) char Bs[2][TJ * ROWB];     // 2 x 16 KB

    const int t = threadIdx.x;
    // XCD-chunked bijective swizzle (nwg=512, 512%8==0): HW dispatch i -> XCD i%8;
    // give each XCD a contiguous slab of (b, it) so its L2 keeps one A-panel.
    const int bid = blockIdx.x + (blockIdx.y << 3) + (blockIdx.z << 7);
    const int w   = ((bid & 7) << 6) + (bid >> 3);
    const int jg  = w & 7;          // j-group: 4 tiles of 64 -> cols jg*256..
    const int it  = (w >> 3) & 15;  // i-tile
    const int b   = w >> 7;         // batch

    const char* xbase = (const char*)xb + (size_t)b * NN * ROWB;
    const char* srcA  = xbase + (size_t)it * TI * ROWB;
    const char* srcB  = xbase + (size_t)(jg * NJI) * TJ * ROWB;

    // ---- stage A (32 KB) + B0 (16 KB), async, drained by first barrier
    #pragma unroll
    for (int i = 0; i < 8; ++i) {
        const int off = (t + i * 256) * 16;
        gload_lds16(srcA + off, As + off);
    }
    #pragma unroll
    for (int i = 0; i < 4; ++i) {
        const int off = (t + i * 256) * 16;
        gload_lds16(srcB + off, (char*)Bs[0] + off);
    }

    const int wave = t >> 6;
    const int lane = t & 63;
    const int wm = (wave >> 1) * 64;
    const int wn = (wave & 1) * 32;
    const int lm = lane & 15;
    const int q  = lane >> 4;
    const int swz = (lm & 7) << 4;

    const float* sqi  = sq + b * NN + it * TI;
    const float* sqj0 = sq + b * NN + jg * NJI * TJ;
    float si[4];
    #pragma unroll
    for (int mf = 0; mf < 4; ++mf) si[mf] = sqi[wm + mf * 16 + lm];

    __syncthreads();   // vmcnt(0) drain: As + Bs[0] resident

    // ---- hoist A fragments: invariant across all 4 j-tiles (64 VGPRs)
    bf16x8 a[4][4];
    #pragma unroll
    for (int ks = 0; ks < 4; ++ks) {
        const int cb = ks * 64 + q * 16;
        #pragma unroll
        for (int mf = 0; mf < 4; ++mf)
            a[ks][mf] = *(const bf16x8*)(As + (wm + mf * 16 + lm) * ROWB + (cb ^ swz));
    }

    float* outb = out + ((size_t)b * NN + (size_t)it * TI) * NN
                      + (size_t)(jg * NJI) * TJ;

    #pragma unroll
    for (int jj = 0; jj < NJI; ++jj) {
        // prefetch next B tile into the other buffer (lands during compute/stores)
        if (jj < NJI - 1) {
            const char* nsrc = srcB + (size_t)(jj + 1) * TJ * ROWB;
            char* ndst = (char*)Bs[(jj + 1) & 1];
            #pragma unroll
            for (int i = 0; i < 4; ++i) {
                const int off = (t + i * 256) * 16;
                gload_lds16(nsrc + off, ndst + off);
            }
        }
        f32x4 sj[2];
        #pragma unroll
        for (int nf = 0; nf < 2; ++nf)
            sj[nf] = *(const f32x4*)(sqj0 + jj * TJ + wn + nf * 16 + q * 4);

        const char* Bcur = (const char*)Bs[jj & 1];
        f32x4 acc[4][2] = {};
        #pragma unroll
        for (int ks = 0; ks < 4; ++ks) {
            const int cb = ks * 64 + q * 16;
            bf16x8 bb[2];
            #pragma unroll
            for (int nf = 0; nf < 2; ++nf)
                bb[nf] = *(const bf16x8*)(Bcur + (wn + nf * 16 + lm) * ROWB + (cb ^ swz));
            #pragma unroll
            for (int mf = 0; mf < 4; ++mf)
                #pragma unroll
                for (int nf = 0; nf < 2; ++nf)
                    acc[mf][nf] = __builtin_amdgcn_mfma_f32_16x16x32_bf16(
                        bb[nf], a[ks][mf], acc[mf][nf], 0, 0, 0);
        }

        // ---- epilogue: d = sqrt(max(si + sj - 2*cross, 0) + eps), 16B stores
        #pragma unroll
        for (int mf = 0; mf < 4; ++mf) {
            const int i = wm + mf * 16 + lm;
            float* rowp = outb + (size_t)i * NN + jj * TJ;
            #pragma unroll
            for (int nf = 0; nf < 2; ++nf) {
                f32x4 d;
                #pragma unroll
                for (int r = 0; r < 4; ++r) {
                    float d2 = si[mf] + sj[nf][r] - 2.0f * acc[mf][nf][r];
                    d[r] = fast_sqrt(fmaxf(d2, 0.0f) + 1e-7f);
                }
                *(f32x4*)(rowp + wn + nf * 16 + q * 4) = d;
            }
        }
        __syncthreads();   // drains next-B loads; paces loop at store-drain rate
    }
}

extern "C" void kernel_launch(void* const* d_in, const int* in_sizes, int n_in,
                              void* d_out, int out_size, void* d_ws, size_t ws_size,
                              hipStream_t stream) {
    const float* x = (const float*)d_in[0];
    float* out = (float*)d_out;
    float*  sqw = (float*)d_ws;                       // 8192 f32
    __bf16* xbw = (__bf16*)((char*)d_ws + 32768);     // 2 MB bf16, swizzled
    edm_prep<<<dim3((4 * NN) / 16), dim3(256), 0, stream>>>(x, xbw, sqw);
    edm_main<<<dim3(NN / (TJ * NJI), NN / TI, 4), dim3(256), 0, stream>>>(xbw, sqw, out);
}